// Round 5
// baseline (262.704 us; speedup 1.0000x reference)
//
#include <hip/hip_runtime.h>
#include <hip/hip_bf16.h>
#include <stdint.h>

#define EMB   768
#define HEADS 8
#define HDIM  96
#define SEQ   2048
#define BATCH 4
#define MROWS (BATCH*SEQ)     // 8192

typedef unsigned short ushort_t;
typedef __bf16 bf16x8 __attribute__((ext_vector_type(8)));
typedef float  fx4    __attribute__((ext_vector_type(4)));
typedef uint4  uint4_a  __attribute__((may_alias));
typedef uint2  uint2_a  __attribute__((may_alias));
typedef bf16x8 bf16x8_a __attribute__((may_alias));

__device__ __forceinline__ float bf2f(ushort_t u) {
    uint32_t v = ((uint32_t)u) << 16;
    return __builtin_bit_cast(float, v);
}
__device__ __forceinline__ ushort_t f2bf(float f) {
    uint32_t u = __builtin_bit_cast(uint32_t, f);
    u += 0x7fffu + ((u >> 16) & 1u);   // RNE
    return (ushort_t)(u >> 16);
}
// packed f32x2 -> bf16x2 (v_cvt_pk_bf16_f32); memcpy: __hip_bfloat162 not trivially copyable
__device__ __forceinline__ uint32_t pk2(float a, float b) {
    __hip_bfloat162 h = __float22bfloat162_rn(make_float2(a, b));
    uint32_t r;
    __builtin_memcpy(&r, &h, 4);
    return r;
}
// raw 2^x (input pre-scaled by log2e in the Q projection)
__device__ __forceinline__ float fexp2(float x) {
    float r;
    asm("v_exp_f32 %0, %1" : "=v"(r) : "v"(x));
    return r;
}
// async global->LDS, 16B/lane; LDS dest must be wave-uniform base + lane*16
__device__ __forceinline__ void load_lds16(const void* g, void* l) {
    __builtin_amdgcn_global_load_lds(
        (const __attribute__((address_space(1))) uint32_t*)g,
        (__attribute__((address_space(3))) uint32_t*)l, 16, 0, 0);
}

// flag=1 -> input words are f32; flag=0 -> packed bf16
__global__ __launch_bounds__(256) void detect_f32(const uint32_t* __restrict__ x,
                                                  int* __restrict__ flag) {
    __shared__ int cnt;
    if (threadIdx.x == 0) cnt = 0;
    __syncthreads();
    int local = 0;
    for (int i = threadIdx.x; i < 4096; i += 256) {
        uint32_t e = (x[i] >> 7) & 0xFFu;
        local += (e >= 64u && e <= 143u) ? 1 : 0;
    }
    atomicAdd(&cnt, local);
    __syncthreads();
    if (threadIdx.x == 0) *flag = (cnt < 3500) ? 1 : 0;
}

// ---------------- canonicalize x to bf16 (8 elems/thread) ----------------
__global__ __launch_bounds__(256) void canon_x(const void* __restrict__ src,
        ushort_t* __restrict__ dst, const int* __restrict__ flag) {
    const int i = (blockIdx.x * 256 + threadIdx.x) * 8;
    if (*flag) {
        const float* s = (const float*)src + i;
        float4 a = *(const float4*)s, b = *(const float4*)(s + 4);
        uint32_t tmp[4] = { pk2(a.x, a.y), pk2(a.z, a.w), pk2(b.x, b.y), pk2(b.z, b.w) };
        *(uint4_a*)&dst[i] = *(const uint4_a*)tmp;
    } else {
        *(uint4_a*)&dst[i] = *(const uint4_a*)((const ushort_t*)src + i);
    }
}

// ---------------- weight transpose (+f32->bf16): src[R][C] -> dst[C][R] bf16 ----------------
__global__ __launch_bounds__(256) void transpose_conv(
        const void* __restrict__ vsrc, ushort_t* __restrict__ dst,
        int R, int C, const int* __restrict__ flag)
{
    __shared__ __attribute__((aligned(16))) ushort_t tile[64][72];
    const int c0 = blockIdx.x * 64, r0 = blockIdx.y * 64;
    const int t = threadIdx.x;
    const int isf32 = *flag;
#pragma unroll
    for (int i = 0; i < 2; ++i) {
        int idx = i * 256 + t;
        int r = idx >> 3, c8 = (idx & 7) * 8;
        if (isf32) {
            const float* s = (const float*)vsrc + (size_t)(r0 + r) * C + c0 + c8;
            float4 v0 = *(const float4*)s, v1 = *(const float4*)(s + 4);
            uint32_t tmp[4] = { pk2(v0.x, v0.y), pk2(v0.z, v0.w),
                                pk2(v1.x, v1.y), pk2(v1.z, v1.w) };
            *(uint4_a*)&tile[r][c8] = *(const uint4_a*)tmp;
        } else {
            const ushort_t* s = (const ushort_t*)vsrc + (size_t)(r0 + r) * C + c0 + c8;
            *(uint4_a*)&tile[r][c8] = *(const uint4_a*)s;
        }
    }
    __syncthreads();
#pragma unroll
    for (int i = 0; i < 2; ++i) {
        int idx = i * 256 + t;
        int r = idx >> 3, k8 = (idx & 7) * 8;
        ushort_t tmp[8];
#pragma unroll
        for (int j = 0; j < 8; ++j) tmp[j] = tile[k8 + j][r];
        *(uint4_a*)&dst[(size_t)(c0 + r) * R + r0 + k8] = *(const uint4_a*)tmp;
    }
}

// ---------------- merged QKV GEMM: [8192 x 768] @ Wt1^T[2304 x 768] ----------------
// grid (64, 18) = 1152 blocks, 128x128 tile, BK=32 -- same main loop as proj_gemm
// (16 MFMA per 2-barrier K-step per wave vs 12 in the per-head version).
// Bijective XCD swizzle (1152 % 8 == 0): each XCD works consecutive flat ids ->
// B-panels (128x768x2B = 196 KB) stay L2-resident per XCD.
// Epilogue scatters per element: c -> (h = c/288, dd = (c%288)/3, s = c%3).
// REQUIRES all 32 stage slots (launched only when G == 32).
__global__ __launch_bounds__(256, 2) void qkv_mfma_full(
        const ushort_t* __restrict__ Xc, const ushort_t* __restrict__ Wt1,
        const void* __restrict__ bias,
        ushort_t* __restrict__ stage, const int* __restrict__ flag)
{
    __shared__ __attribute__((aligned(16))) ushort_t lA[128 * 32];
    __shared__ __attribute__((aligned(16))) ushort_t lB[128 * 32];
    const int t = threadIdx.x;
    // XCD swizzle on flat id (grid 64 x 18 = 1152)
    int flat = blockIdx.y * 64 + blockIdx.x;
    int nf = (flat & 7) * 144 + (flat >> 3);
    const int m0 = (nf % 64) * 128;      // M tile (8192 rows)
    const int n0 = (nf / 64) * 128;      // N tile (2304 cols)
    const bool isf = (*flag != 0);
    const int lane = t & 63, wave = t >> 6;
    const int wm = (wave & 1) * 64, wn = (wave >> 1) * 64;
    const int lx = lane & 15, quad = lane >> 4;
    const float qscale = 0.0520587734f;   // log2(e)/sqrt(768)

    fx4 acc[4][4] = {};

    for (int kt = 0; kt < EMB / 32; ++kt) {
        const int k0 = kt * 32;
        __syncthreads();
#pragma unroll
        for (int it = 0; it < 2; ++it) {
            int idx = it * 256 + t;
            int r = idx >> 2, s8 = (idx & 3) * 8;
            load_lds16(&Xc [(size_t)(m0 + r) * EMB + k0 + s8], &lA[idx * 8]);
            load_lds16(&Wt1[(size_t)(n0 + r) * EMB + k0 + s8], &lB[idx * 8]);
        }
        __syncthreads();

        bf16x8 af[4], bfr[4];
#pragma unroll
        for (int i = 0; i < 4; ++i)
            af[i] = *(const bf16x8_a*)&lA[(wm + i * 16 + lx) * 32 + quad * 8];
#pragma unroll
        for (int j = 0; j < 4; ++j)
            bfr[j] = *(const bf16x8_a*)&lB[(wn + j * 16 + lx) * 32 + quad * 8];
#pragma unroll
        for (int i = 0; i < 4; ++i)
#pragma unroll
            for (int j = 0; j < 4; ++j)
                acc[i][j] = __builtin_amdgcn_mfma_f32_16x16x32_bf16(af[i], bfr[j], acc[i][j], 0, 0, 0);
    }

    // epilogue: C/D col=lane&15, row=quad*4+reg.  c -> (h, dd, s); b from m0.
    const int b = m0 >> 11;              // 128-row tiles never straddle a batch
    const int mbase = (m0 & 2047) + wm + quad * 4;
#pragma unroll
    for (int j = 0; j < 4; ++j) {
        const int c = n0 + wn + j * 16 + lx;
        const int h = c / 288;
        const int cl = c - h * 288;
        const int dd = cl / 3, s = cl - dd * 3;
        const float bv = isf ? ((const float*)bias)[c]
                             : bf2f(((const ushort_t*)bias)[c]);
        ushort_t* Qg = stage + (size_t)(b * 8 + h) * (3 * SEQ * HDIM);
        ushort_t* Kg = Qg + SEQ * HDIM;
        ushort_t* Vg = Qg + 2 * SEQ * HDIM;
#pragma unroll
        for (int i = 0; i < 4; ++i) {
            const int ml = mbase + i * 16;
#pragma unroll
            for (int r = 0; r < 4; ++r) {
                const int nseq = ml + r;
                const float v = acc[i][j][r] + bv;
                if (s == 0)      Qg[(size_t)nseq * HDIM + dd] = f2bf(v * qscale);
                else if (s == 1) Kg[(size_t)nseq * HDIM + dd] = f2bf(v);
                else             Vg[(size_t)dd * SEQ + nseq] = f2bf(v);
            }
        }
    }
}

// ---------------- per-head QKV GEMM (fallback when G < 32) ----------------
__global__ __launch_bounds__(256, 2) void qkv_mfma(
        const ushort_t* __restrict__ Xc, const ushort_t* __restrict__ Wt1,
        const void* __restrict__ bias,
        ushort_t* __restrict__ stage, int u0, const int* __restrict__ flag)
{
    __shared__ __attribute__((aligned(16))) ushort_t lA[128 * 32];
    __shared__ __attribute__((aligned(16))) ushort_t lB[96 * 32];
    const int g = blockIdx.z, u = u0 + g;
    const int b = u >> 3, h = u & 7;
    const int m0 = blockIdx.x * 128;
    const int n0 = blockIdx.y * 96;
    const bool isf = (*flag != 0);
    const int t = threadIdx.x, lane = t & 63, wave = t >> 6;
    const int lx = lane & 15, quad = lane >> 4;
    const int wm = (wave & 1) * 64, wn = (wave >> 1) * 48;
    const int hb = h * 288;
    const size_t xrow0 = (size_t)(b * SEQ + m0) * EMB;
    const float qscale = 0.0520587734f;   // log2(e)/sqrt(768)

    ushort_t* Qg = stage + (size_t)g * (3 * SEQ * HDIM);
    ushort_t* Kg = Qg + SEQ * HDIM;
    ushort_t* Vg = Qg + 2 * SEQ * HDIM;

    fx4 acc[4][3] = {};

    for (int kt = 0; kt < EMB / 32; ++kt) {
        const int k0 = kt * 32;
        __syncthreads();
#pragma unroll
        for (int it = 0; it < 2; ++it) {
            int idx = it * 256 + t;
            int r = idx >> 2, k8 = (idx & 3) * 8;
            load_lds16(&Xc[xrow0 + (size_t)r * EMB + k0 + k8], &lA[idx * 8]);
        }
        {
            int c = t >> 2, s8 = (t & 3) * 8;
            load_lds16(&Wt1[(size_t)(hb + n0 + c) * EMB + k0 + s8], &lB[t * 8]);
            if (t < 128) {
                int idx = 256 + t;
                int c2 = idx >> 2, s82 = (idx & 3) * 8;
                load_lds16(&Wt1[(size_t)(hb + n0 + c2) * EMB + k0 + s82], &lB[idx * 8]);
            }
        }
        __syncthreads();

        bf16x8 af[4], bfr[3];
#pragma unroll
        for (int i = 0; i < 4; ++i)
            af[i] = *(const bf16x8_a*)&lA[(wm + i * 16 + lx) * 32 + quad * 8];
#pragma unroll
        for (int j = 0; j < 3; ++j)
            bfr[j] = *(const bf16x8_a*)&lB[(wn + j * 16 + lx) * 32 + quad * 8];
#pragma unroll
        for (int i = 0; i < 4; ++i)
#pragma unroll
            for (int j = 0; j < 3; ++j)
                acc[i][j] = __builtin_amdgcn_mfma_f32_16x16x32_bf16(af[i], bfr[j], acc[i][j], 0, 0, 0);
    }

#pragma unroll
    for (int j = 0; j < 3; ++j) {
        const int cl = n0 + wn + j * 16 + lx;
        const int dd = cl / 3, s = cl - dd * 3;
        const float bv = isf ? ((const float*)bias)[hb + cl]
                             : bf2f(((const ushort_t*)bias)[hb + cl]);
#pragma unroll
        for (int i = 0; i < 4; ++i) {
            const int ml = m0 + wm + i * 16 + quad * 4;
#pragma unroll
            for (int r = 0; r < 4; ++r) {
                const int nseq = ml + r;
                const float v = acc[i][j][r] + bv;
                if (s == 0)      Qg[(size_t)nseq * HDIM + dd] = f2bf(v * qscale);
                else if (s == 1) Kg[(size_t)nseq * HDIM + dd] = f2bf(v);
                else             Vg[(size_t)dd * SEQ + nseq] = f2bf(v);
            }
        }
    }
}

// ---------------- flash attention v2: 128 q-rows/block, 32 q-rows/wave ----------------
// grid (SEQ/128=16, gc). Proven 2-barrier staging structure (round-3, 84.4us):
//  * Q held in registers (loaded once from global)
//  * XCD swizzle (FETCH_SIZE -79%, K/V L2-resident)
//  * softmax via raw v_exp_f32 (log2e folded into Q scale upstream)
// LDS 35.5 KB; occupancy VGPR-capped at 2 blocks/CU.
__global__ __launch_bounds__(256, 2) void attn_flash(
        const ushort_t* __restrict__ stage, ushort_t* __restrict__ O, int u0)
{
    __shared__ __attribute__((aligned(16))) ushort_t lK[64 * 104];   // 13.0 KB
    __shared__ __attribute__((aligned(16))) ushort_t lV[96 * 72];    // 13.5 KB
    __shared__ __attribute__((aligned(16))) ushort_t lP[4][16 * 72]; //  9.0 KB wave-private
    const int t = threadIdx.x, lane = t & 63, wave = t >> 6;
    const int lx = lane & 15, quad = lane >> 4;
    int qt = blockIdx.x, g = blockIdx.y;
    if (gridDim.y == 32) {
        // XCD-aware swizzle (bijective on the 16x32 grid): each XCD owns 4
        // consecutive (b,h) units -> all 16 q-blocks of a unit share one L2.
        int L = blockIdx.y * 16 + blockIdx.x;
        int xcd = L & 7, i = L >> 3;
        g = xcd * 4 + (i >> 4);
        qt = i & 15;
    }
    const int u = u0 + g;
    const int b = u >> 3, h = u & 7;
    const ushort_t* Qb = stage + (size_t)g * (3 * SEQ * HDIM);
    const ushort_t* Kb = Qb + SEQ * HDIM;
    const ushort_t* Vb = Qb + 2 * SEQ * HDIM;

    // ---- Q fragments in registers, loaded once from global ----
    bf16x8 aq[2][3];
#pragma unroll
    for (int i = 0; i < 2; ++i)
#pragma unroll
        for (int kd = 0; kd < 3; ++kd)
            aq[i][kd] = *(const bf16x8_a*)
                &Qb[(size_t)(qt * 128 + wave * 32 + i * 16 + lx) * HDIM + kd * 32 + quad * 8];

    fx4 accO[2][6] = {};
    float lsum[2][4] = {};

    for (int kt = 0; kt < SEQ / 64; ++kt) {
        __syncthreads();
        // stage K (64x96) and V (96x64) tiles: 768 16B segs each, 3 per thread
#pragma unroll
        for (int it = 0; it < 3; ++it) {
            int idx = it * 256 + t;
            { int r = idx / 12, s8 = (idx % 12) * 8;
              *(uint4_a*)&lK[r * 104 + s8] = *(const uint4_a*)&Kb[(size_t)(kt * 64 + r) * HDIM + s8]; }
            { int r = idx >> 3, s8 = (idx & 7) * 8;
              *(uint4_a*)&lV[r * 72 + s8] = *(const uint4_a*)&Vb[(size_t)r * SEQ + kt * 64 + s8]; }
        }
        __syncthreads();

        // S = Qs*K^T : wave covers 32 q-rows (2 m-frags) x 64 keys
        fx4 accS[2][4] = {};
#pragma unroll
        for (int kd = 0; kd < 3; ++kd) {
#pragma unroll
            for (int j = 0; j < 4; ++j) {
                bf16x8 bk = *(const bf16x8_a*)&lK[(j * 16 + lx) * 104 + kd * 32 + quad * 8];
                accS[0][j] = __builtin_amdgcn_mfma_f32_16x16x32_bf16(aq[0][kd], bk, accS[0][j], 0, 0, 0);
                accS[1][j] = __builtin_amdgcn_mfma_f32_16x16x32_bf16(aq[1][kd], bk, accS[1][j], 0, 0, 0);
            }
        }

        // preload V fragments once (shared across both m half-passes)
        bf16x8 bv[2][6];
#pragma unroll
        for (int kk = 0; kk < 2; ++kk)
#pragma unroll
            for (int d = 0; d < 6; ++d)
                bv[kk][d] = *(const bf16x8_a*)&lV[(d * 16 + lx) * 72 + kk * 32 + quad * 8];

        // two half-passes over m-frags, reusing lP[wave]
#pragma unroll
        for (int i = 0; i < 2; ++i) {
#pragma unroll
            for (int r = 0; r < 4; ++r) {
#pragma unroll
                for (int j = 0; j < 4; ++j) {
                    float p = fexp2(accS[i][j][r]);   // 2^x, log2e folded into Q
                    lsum[i][r] += p;
                    lP[wave][(quad * 4 + r) * 72 + j * 16 + lx] = f2bf(p);
                }
            }
            asm volatile("s_waitcnt lgkmcnt(0)" ::: "memory");  // wave-private lP drained
#pragma unroll
            for (int kk = 0; kk < 2; ++kk) {
                bf16x8 ap = *(const bf16x8_a*)&lP[wave][lx * 72 + kk * 32 + quad * 8];
#pragma unroll
                for (int d = 0; d < 6; ++d)
                    accO[i][d] = __builtin_amdgcn_mfma_f32_16x16x32_bf16(ap, bv[kk][d], accO[i][d], 0, 0, 0);
            }
        }
    }

    // epilogue
#pragma unroll
    for (int i = 0; i < 2; ++i) {
#pragma unroll
        for (int r = 0; r < 4; ++r) {
            float s = lsum[i][r];
#pragma unroll
            for (int off = 1; off < 16; off <<= 1) s += __shfl_xor(s, off, 64);
            const float inv = 1.0f / s;
            const int nseq = qt * 128 + wave * 32 + i * 16 + quad * 4 + r;
            ushort_t* orow = O + ((size_t)(b * SEQ + nseq)) * EMB + h * HDIM;
#pragma unroll
            for (int d = 0; d < 6; ++d)
                orow[d * 16 + lx] = f2bf(accO[i][d][r] * inv);
        }
    }
}

// ---------------- projection: Ob bf16 [8192][768] @ Wt2^T + bias -> f32 out ----------------
__global__ __launch_bounds__(256, 2) void proj_gemm(
        const ushort_t* __restrict__ A, const ushort_t* __restrict__ Wt2,
        const void* __restrict__ bias, float* __restrict__ out,
        const int* __restrict__ flag)
{
    constexpr int KDIM = EMB;
    __shared__ __attribute__((aligned(16))) ushort_t lA[128 * 32];
    __shared__ __attribute__((aligned(16))) ushort_t lB[128 * 32];
    const int t = threadIdx.x;
    const int m0 = blockIdx.x * 128, n0 = blockIdx.y * 128;
    const bool isf = (*flag != 0);
    const int lane = t & 63, wave = t >> 6;
    const int wm = (wave & 1) * 64, wn = (wave >> 1) * 64;
    const int lx = lane & 15, quad = lane >> 4;

    fx4 acc[4][4] = {};

    for (int kt = 0; kt < KDIM / 32; ++kt) {
        const int k0 = kt * 32;
        __syncthreads();
#pragma unroll
        for (int it = 0; it < 2; ++it) {
            int idx = it * 256 + t;
            int r = idx >> 2, s8 = (idx & 3) * 8;
            load_lds16(&A  [(size_t)(m0 + r) * KDIM + k0 + s8], &lA[idx * 8]);
            load_lds16(&Wt2[(size_t)(n0 + r) * KDIM + k0 + s8], &lB[idx * 8]);
        }
        __syncthreads();

        bf16x8 af[4], bfr[4];
#pragma unroll
        for (int i = 0; i < 4; ++i)
            af[i] = *(const bf16x8_a*)&lA[(wm + i * 16 + lx) * 32 + quad * 8];
#pragma unroll
        for (int j = 0; j < 4; ++j)
            bfr[j] = *(const bf16x8_a*)&lB[(wn + j * 16 + lx) * 32 + quad * 8];
#pragma unroll
        for (int i = 0; i < 4; ++i)
#pragma unroll
            for (int j = 0; j < 4; ++j)
                acc[i][j] = __builtin_amdgcn_mfma_f32_16x16x32_bf16(af[i], bfr[j], acc[i][j], 0, 0, 0);
    }

#pragma unroll
    for (int j = 0; j < 4; ++j) {
        const int c = n0 + wn + j * 16 + lx;
        const float bv = isf ? ((const float*)bias)[c] : bf2f(((const ushort_t*)bias)[c]);
#pragma unroll
        for (int i = 0; i < 4; ++i) {
            const int mr = m0 + wm + i * 16 + quad * 4;
#pragma unroll
            for (int r = 0; r < 4; ++r)
                out[(size_t)(mr + r) * EMB + c] = acc[i][j][r] + bv;   // f32 store
        }
    }
}

// ---------------- launch ----------------
extern "C" void kernel_launch(void* const* d_in, const int* in_sizes, int n_in,
                              void* d_out, int out_size, void* d_ws, size_t ws_size,
                              hipStream_t stream) {
    const void* x     = d_in[0];
    const void* Wqkv  = d_in[1];
    const void* bqkv  = d_in[2];
    const void* Wproj = d_in[3];
    const void* bproj = d_in[4];
    float* out = (float*)d_out;     // output is float32

    char* ws = (char*)d_ws;
    int* flag = (int*)ws;
    size_t off = 1024;
    ushort_t* Ob  = (ushort_t*)(ws + off);  off += (size_t)MROWS * EMB * 2;   // 12.58 MB
    ushort_t* Xc  = (ushort_t*)(ws + off);  off += (size_t)MROWS * EMB * 2;   // 12.58 MB
    ushort_t* Wt1 = (ushort_t*)(ws + off);  off += (size_t)2304 * EMB * 2;    //  3.54 MB
    ushort_t* Wt2 = (ushort_t*)(ws + off);  off += (size_t)EMB * EMB * 2;     //  1.18 MB
    ushort_t* stage = (ushort_t*)(ws + off);
    const size_t SLOT_BYTES = (size_t)3 * SEQ * HDIM * 2;   // 1.18 MB per (b,h) unit
    size_t avail = ws_size > off ? ws_size - off : 0;
    int G = (int)(avail / SLOT_BYTES);
    if (G < 1) G = 1;
    if (G > 32) G = 32;

    detect_f32<<<1, 256, 0, stream>>>((const uint32_t*)x, flag);
    canon_x<<<dim3(MROWS * EMB / (256 * 8)), 256, 0, stream>>>(x, Xc, flag);
    transpose_conv<<<dim3(2304 / 64, EMB / 64), 256, 0, stream>>>(Wqkv, Wt1, EMB, 2304, flag);
    transpose_conv<<<dim3(EMB / 64, EMB / 64), 256, 0, stream>>>(Wproj, Wt2, EMB, EMB, flag);
    if (G == 32) {
        // merged QKV over all heads (requires all 32 stage slots)
        qkv_mfma_full<<<dim3(64, 18), 256, 0, stream>>>(Xc, Wt1, bqkv, stage, flag);
        attn_flash<<<dim3(SEQ / 128, 32), 256, 0, stream>>>(stage, Ob, 0);
    } else {
        for (int u0 = 0; u0 < 32; u0 += G) {
            const int gc = (32 - u0 < G) ? (32 - u0) : G;
            qkv_mfma<<<dim3(16, 3, gc), 256, 0, stream>>>(Xc, Wt1, bqkv, stage, u0, flag);
            attn_flash<<<dim3(SEQ / 128, gc), 256, 0, stream>>>(stage, Ob, u0);
        }
    }
    proj_gemm<<<dim3(MROWS / 128, EMB / 128), 256, 0, stream>>>(Ob, Wt2, bproj, out, flag);
}

// Round 7
// 248.767 us; speedup vs baseline: 1.0560x; 1.0560x over previous
//
#include <hip/hip_runtime.h>
#include <hip/hip_bf16.h>
#include <stdint.h>

#define EMB   768
#define HEADS 8
#define HDIM  96
#define SEQ   2048
#define BATCH 4
#define MROWS (BATCH*SEQ)     // 8192

typedef unsigned short ushort_t;
typedef __bf16 bf16x8 __attribute__((ext_vector_type(8)));
typedef float  fx4    __attribute__((ext_vector_type(4)));
typedef uint4  uint4_a  __attribute__((may_alias));
typedef uint2  uint2_a  __attribute__((may_alias));
typedef bf16x8 bf16x8_a __attribute__((may_alias));

__device__ __forceinline__ float bf2f(ushort_t u) {
    uint32_t v = ((uint32_t)u) << 16;
    return __builtin_bit_cast(float, v);
}
__device__ __forceinline__ ushort_t f2bf(float f) {
    uint32_t u = __builtin_bit_cast(uint32_t, f);
    u += 0x7fffu + ((u >> 16) & 1u);   // RNE
    return (ushort_t)(u >> 16);
}
// packed f32x2 -> bf16x2 (v_cvt_pk_bf16_f32); memcpy: __hip_bfloat162 not trivially copyable
__device__ __forceinline__ uint32_t pk2(float a, float b) {
    __hip_bfloat162 h = __float22bfloat162_rn(make_float2(a, b));
    uint32_t r;
    __builtin_memcpy(&r, &h, 4);
    return r;
}
// raw 2^x (input pre-scaled by log2e in the Q projection)
__device__ __forceinline__ float fexp2(float x) {
    float r;
    asm("v_exp_f32 %0, %1" : "=v"(r) : "v"(x));
    return r;
}
// async global->LDS, 16B/lane; LDS dest must be wave-uniform base + lane*16
__device__ __forceinline__ void load_lds16(const void* g, void* l) {
    __builtin_amdgcn_global_load_lds(
        (const __attribute__((address_space(1))) uint32_t*)g,
        (__attribute__((address_space(3))) uint32_t*)l, 16, 0, 0);
}

// flag=1 -> input words are f32; flag=0 -> packed bf16
__global__ __launch_bounds__(256) void detect_f32(const uint32_t* __restrict__ x,
                                                  int* __restrict__ flag) {
    __shared__ int cnt;
    if (threadIdx.x == 0) cnt = 0;
    __syncthreads();
    int local = 0;
    for (int i = threadIdx.x; i < 4096; i += 256) {
        uint32_t e = (x[i] >> 7) & 0xFFu;
        local += (e >= 64u && e <= 143u) ? 1 : 0;
    }
    atomicAdd(&cnt, local);
    __syncthreads();
    if (threadIdx.x == 0) *flag = (cnt < 3500) ? 1 : 0;
}

// ---------------- canonicalize x to bf16 (8 elems/thread) ----------------
__global__ __launch_bounds__(256) void canon_x(const void* __restrict__ src,
        ushort_t* __restrict__ dst, const int* __restrict__ flag) {
    const int i = (blockIdx.x * 256 + threadIdx.x) * 8;
    if (*flag) {
        const float* s = (const float*)src + i;
        float4 a = *(const float4*)s, b = *(const float4*)(s + 4);
        uint32_t tmp[4] = { pk2(a.x, a.y), pk2(a.z, a.w), pk2(b.x, b.y), pk2(b.z, b.w) };
        *(uint4_a*)&dst[i] = *(const uint4_a*)tmp;
    } else {
        *(uint4_a*)&dst[i] = *(const uint4_a*)((const ushort_t*)src + i);
    }
}

// ---------------- weight transpose (+f32->bf16): src[R][C] -> dst[C'][R] bf16 ---------
// permQKV=1: destination row for src column c is n = h*288 + s*96 + dd
// (h=c/288, dd=(c%288)/3, s=c%3) -- de-interleaves the fused qkv so the GEMM's
// N dimension becomes contiguous {Q|K|V} sections (kills the epilogue scatter).
__global__ __launch_bounds__(256) void transpose_conv(
        const void* __restrict__ vsrc, ushort_t* __restrict__ dst,
        int R, int C, const int* __restrict__ flag, int permQKV)
{
    __shared__ __attribute__((aligned(16))) ushort_t tile[64][72];
    const int c0 = blockIdx.x * 64, r0 = blockIdx.y * 64;
    const int t = threadIdx.x;
    const int isf32 = *flag;
#pragma unroll
    for (int i = 0; i < 2; ++i) {
        int idx = i * 256 + t;
        int r = idx >> 3, c8 = (idx & 7) * 8;
        if (isf32) {
            const float* s = (const float*)vsrc + (size_t)(r0 + r) * C + c0 + c8;
            float4 v0 = *(const float4*)s, v1 = *(const float4*)(s + 4);
            uint32_t tmp[4] = { pk2(v0.x, v0.y), pk2(v0.z, v0.w),
                                pk2(v1.x, v1.y), pk2(v1.z, v1.w) };
            *(uint4_a*)&tile[r][c8] = *(const uint4_a*)tmp;
        } else {
            const ushort_t* s = (const ushort_t*)vsrc + (size_t)(r0 + r) * C + c0 + c8;
            *(uint4_a*)&tile[r][c8] = *(const uint4_a*)s;
        }
    }
    __syncthreads();
#pragma unroll
    for (int i = 0; i < 2; ++i) {
        int idx = i * 256 + t;
        int r = idx >> 3, k8 = (idx & 7) * 8;
        ushort_t tmp[8];
#pragma unroll
        for (int j = 0; j < 8; ++j) tmp[j] = tile[k8 + j][r];
        int cdst = c0 + r;
        if (permQKV) {
            int h = cdst / 288, rem = cdst - h * 288;
            cdst = h * 288 + (rem % 3) * 96 + rem / 3;
        }
        *(uint4_a*)&dst[(size_t)cdst * R + r0 + k8] = *(const uint4_a*)tmp;
    }
}

// ---------------- QKV GEMM, permuted weights, section tiles ----------------
// grid (64, 24) = 1536 blocks; tile 128(M) x 96(N); BK=32.
// With permuted Wt1, N-tile sec = h*3+s is a UNIFORM section (all-Q, all-K or
// all-V of one head) -> epilogue repacks acc through LDS (padded strides, <=2-way
// bank aliasing) and stores 16B/lane fully coalesced:
//   Q/K: [nseq][96] rows (192B contiguous);  V: [dd][2048] chunks of 256B.
// Zero partial-line writes -> no RFO fetch, no write amplification
// (round-5 counters: 84MB FETCH + 94MB WRITE from the per-element scatter).
// Bijective XCD swizzle: 192 blocks/XCD = 3 whole B-sections L2-resident.
__global__ __launch_bounds__(256, 2) void qkv_mfma_perm(
        const ushort_t* __restrict__ Xc, const ushort_t* __restrict__ Wt1p,
        const void* __restrict__ bias,
        ushort_t* __restrict__ stage, const int* __restrict__ flag)
{
    __shared__ __attribute__((aligned(16))) ushort_t lA[128 * 32];   //  8.0 KB
    __shared__ __attribute__((aligned(16))) ushort_t lB[96 * 32];    //  6.0 KB
    __shared__ __attribute__((aligned(16))) ushort_t lT[13312];      // 26.0 KB repack
    const int t = threadIdx.x;
    const int flat = blockIdx.y * 64 + blockIdx.x;     // [0,1536)
    const int nf = (flat & 7) * 192 + (flat >> 3);     // bijective XCD swizzle
    const int mt = nf & 63, sec = nf >> 6;             // m-tile, section h*3+s
    const int h = sec / 3, s = sec - h * 3;
    const int m0 = mt * 128;
    const bool isf = (*flag != 0);
    const int lane = t & 63, wave = t >> 6;
    const int lx = lane & 15, quad = lane >> 4;
    const int wm = (wave & 1) * 64, wn = (wave >> 1) * 48;
    const float qscale = 0.0520587734f;   // log2(e)/sqrt(768)

    fx4 acc[4][3] = {};

    for (int kt = 0; kt < EMB / 32; ++kt) {
        const int k0 = kt * 32;
        __syncthreads();
        // A tile via DMA: 512 segs (128 rows x 4)
#pragma unroll
        for (int it = 0; it < 2; ++it) {
            int idx = it * 256 + t;
            int r = idx >> 2, k8 = (idx & 3) * 8;
            load_lds16(&Xc[(size_t)(m0 + r) * EMB + k0 + k8], &lA[idx * 8]);
        }
        // B tile via DMA: 384 segs (96 rows x 4), rows sec*96 + c
        {
            int c = t >> 2, s8 = (t & 3) * 8;
            load_lds16(&Wt1p[(size_t)(sec * 96 + c) * EMB + k0 + s8], &lB[t * 8]);
            if (t < 128) {
                int idx = 256 + t;
                int c2 = idx >> 2, s82 = (idx & 3) * 8;
                load_lds16(&Wt1p[(size_t)(sec * 96 + c2) * EMB + k0 + s82], &lB[idx * 8]);
            }
        }
        __syncthreads();

        bf16x8 af[4], bfr[3];
#pragma unroll
        for (int i = 0; i < 4; ++i)
            af[i] = *(const bf16x8_a*)&lA[(wm + i * 16 + lx) * 32 + quad * 8];
#pragma unroll
        for (int j = 0; j < 3; ++j)
            bfr[j] = *(const bf16x8_a*)&lB[(wn + j * 16 + lx) * 32 + quad * 8];
#pragma unroll
        for (int i = 0; i < 4; ++i)
#pragma unroll
            for (int j = 0; j < 3; ++j)
                acc[i][j] = __builtin_amdgcn_mfma_f32_16x16x32_bf16(af[i], bfr[j], acc[i][j], 0, 0, 0);
    }

    // ---- coalesced epilogue via LDS repack ----
    // C/D frag: col dd = wn + j*16 + lx, row = wm + i*16 + quad*4 + r.
    const int b8 = (m0 >> 11) * 8, mrow = m0 & 2047;   // 128-row tiles never straddle a batch
    ushort_t* base = stage + (size_t)(b8 + h) * (3 * SEQ * HDIM);
    if (s < 2) {
        // Q/K: lT row-major [128][104 pad], then 16B stores of [nseq][96] rows
        ushort_t* dstQK = base + (size_t)s * SEQ * HDIM;
        const float sc = (s == 0) ? qscale : 1.0f;
#pragma unroll
        for (int j = 0; j < 3; ++j) {
            const int dd = wn + j * 16 + lx;
            const int c = h * 288 + dd * 3 + s;        // original column for bias
            const float bv = isf ? ((const float*)bias)[c]
                                 : bf2f(((const ushort_t*)bias)[c]);
#pragma unroll
            for (int i = 0; i < 4; ++i)
#pragma unroll
                for (int r = 0; r < 4; ++r)
                    lT[(wm + i * 16 + quad * 4 + r) * 104 + dd] = f2bf((acc[i][j][r] + bv) * sc);
        }
        __syncthreads();
#pragma unroll
        for (int it = 0; it < 6; ++it) {
            int idx = it * 256 + t;                    // 1536 segs = 128 rows x 12
            int r = idx / 12, s8 = (idx % 12) * 8;
            *(uint4_a*)&dstQK[(size_t)(mrow + r) * HDIM + s8] = *(const uint4_a*)&lT[r * 104 + s8];
        }
    } else {
        // V: lT transposed [96][136 pad], then 16B stores of [dd][2048] chunks
        ushort_t* Vg = base + 2 * SEQ * HDIM;
#pragma unroll
        for (int j = 0; j < 3; ++j) {
            const int dd = wn + j * 16 + lx;
            const int c = h * 288 + dd * 3 + 2;
            const float bv = isf ? ((const float*)bias)[c]
                                 : bf2f(((const ushort_t*)bias)[c]);
#pragma unroll
            for (int i = 0; i < 4; ++i)
#pragma unroll
                for (int r = 0; r < 4; ++r)
                    lT[dd * 136 + wm + i * 16 + quad * 4 + r] = f2bf(acc[i][j][r] + bv);
        }
        __syncthreads();
#pragma unroll
        for (int it = 0; it < 6; ++it) {
            int idx = it * 256 + t;                    // 1536 segs = 96 rows x 16
            int dd = idx >> 4, s8 = (idx & 15) * 8;
            *(uint4_a*)&Vg[(size_t)dd * SEQ + mrow + s8] = *(const uint4_a*)&lT[dd * 136 + s8];
        }
    }
}

// ---------------- per-head QKV GEMM (fallback when G < 32; unpermuted Wt1) --------
__global__ __launch_bounds__(256, 2) void qkv_mfma(
        const ushort_t* __restrict__ Xc, const ushort_t* __restrict__ Wt1,
        const void* __restrict__ bias,
        ushort_t* __restrict__ stage, int u0, const int* __restrict__ flag)
{
    __shared__ __attribute__((aligned(16))) ushort_t lA[128 * 32];
    __shared__ __attribute__((aligned(16))) ushort_t lB[96 * 32];
    const int g = blockIdx.z, u = u0 + g;
    const int b = u >> 3, h = u & 7;
    const int m0 = blockIdx.x * 128;
    const int n0 = blockIdx.y * 96;
    const bool isf = (*flag != 0);
    const int t = threadIdx.x, lane = t & 63, wave = t >> 6;
    const int lx = lane & 15, quad = lane >> 4;
    const int wm = (wave & 1) * 64, wn = (wave >> 1) * 48;
    const int hb = h * 288;
    const size_t xrow0 = (size_t)(b * SEQ + m0) * EMB;
    const float qscale = 0.0520587734f;   // log2(e)/sqrt(768)

    ushort_t* Qg = stage + (size_t)g * (3 * SEQ * HDIM);
    ushort_t* Kg = Qg + SEQ * HDIM;
    ushort_t* Vg = Qg + 2 * SEQ * HDIM;

    fx4 acc[4][3] = {};

    for (int kt = 0; kt < EMB / 32; ++kt) {
        const int k0 = kt * 32;
        __syncthreads();
#pragma unroll
        for (int it = 0; it < 2; ++it) {
            int idx = it * 256 + t;
            int r = idx >> 2, k8 = (idx & 3) * 8;
            load_lds16(&Xc[xrow0 + (size_t)r * EMB + k0 + k8], &lA[idx * 8]);
        }
        {
            int c = t >> 2, s8 = (t & 3) * 8;
            load_lds16(&Wt1[(size_t)(hb + n0 + c) * EMB + k0 + s8], &lB[t * 8]);
            if (t < 128) {
                int idx = 256 + t;
                int c2 = idx >> 2, s82 = (idx & 3) * 8;
                load_lds16(&Wt1[(size_t)(hb + n0 + c2) * EMB + k0 + s82], &lB[idx * 8]);
            }
        }
        __syncthreads();

        bf16x8 af[4], bfr[3];
#pragma unroll
        for (int i = 0; i < 4; ++i)
            af[i] = *(const bf16x8_a*)&lA[(wm + i * 16 + lx) * 32 + quad * 8];
#pragma unroll
        for (int j = 0; j < 3; ++j)
            bfr[j] = *(const bf16x8_a*)&lB[(wn + j * 16 + lx) * 32 + quad * 8];
#pragma unroll
        for (int i = 0; i < 4; ++i)
#pragma unroll
            for (int j = 0; j < 3; ++j)
                acc[i][j] = __builtin_amdgcn_mfma_f32_16x16x32_bf16(af[i], bfr[j], acc[i][j], 0, 0, 0);
    }

#pragma unroll
    for (int j = 0; j < 3; ++j) {
        const int cl = n0 + wn + j * 16 + lx;
        const int dd = cl / 3, s = cl - dd * 3;
        const float bv = isf ? ((const float*)bias)[hb + cl]
                             : bf2f(((const ushort_t*)bias)[hb + cl]);
#pragma unroll
        for (int i = 0; i < 4; ++i) {
            const int ml = m0 + wm + i * 16 + quad * 4;
#pragma unroll
            for (int r = 0; r < 4; ++r) {
                const int nseq = ml + r;
                const float v = acc[i][j][r] + bv;
                if (s == 0)      Qg[(size_t)nseq * HDIM + dd] = f2bf(v * qscale);
                else if (s == 1) Kg[(size_t)nseq * HDIM + dd] = f2bf(v);
                else             Vg[(size_t)dd * SEQ + nseq] = f2bf(v);
            }
        }
    }
}

// ---------------- flash attention v2: 128 q-rows/block, 32 q-rows/wave ----------------
// grid (SEQ/128=16, gc). Proven 2-barrier staging structure (round-3, 84.4us):
//  * Q held in registers (loaded once from global)
//  * XCD swizzle (FETCH_SIZE -79%, K/V L2-resident)
//  * softmax via raw v_exp_f32 (log2e folded into Q scale upstream)
// LDS 35.5 KB; occupancy VGPR-capped at 2 blocks/CU.
__global__ __launch_bounds__(256, 2) void attn_flash(
        const ushort_t* __restrict__ stage, ushort_t* __restrict__ O, int u0)
{
    __shared__ __attribute__((aligned(16))) ushort_t lK[64 * 104];   // 13.0 KB
    __shared__ __attribute__((aligned(16))) ushort_t lV[96 * 72];    // 13.5 KB
    __shared__ __attribute__((aligned(16))) ushort_t lP[4][16 * 72]; //  9.0 KB wave-private
    const int t = threadIdx.x, lane = t & 63, wave = t >> 6;
    const int lx = lane & 15, quad = lane >> 4;
    int qt = blockIdx.x, g = blockIdx.y;
    if (gridDim.y == 32) {
        // XCD-aware swizzle (bijective on the 16x32 grid): each XCD owns 4
        // consecutive (b,h) units -> all 16 q-blocks of a unit share one L2.
        int L = blockIdx.y * 16 + blockIdx.x;
        int xcd = L & 7, i = L >> 3;
        g = xcd * 4 + (i >> 4);
        qt = i & 15;
    }
    const int u = u0 + g;
    const int b = u >> 3, h = u & 7;
    const ushort_t* Qb = stage + (size_t)g * (3 * SEQ * HDIM);
    const ushort_t* Kb = Qb + SEQ * HDIM;
    const ushort_t* Vb = Qb + 2 * SEQ * HDIM;

    // ---- Q fragments in registers, loaded once from global ----
    bf16x8 aq[2][3];
#pragma unroll
    for (int i = 0; i < 2; ++i)
#pragma unroll
        for (int kd = 0; kd < 3; ++kd)
            aq[i][kd] = *(const bf16x8_a*)
                &Qb[(size_t)(qt * 128 + wave * 32 + i * 16 + lx) * HDIM + kd * 32 + quad * 8];

    fx4 accO[2][6] = {};
    float lsum[2][4] = {};

    for (int kt = 0; kt < SEQ / 64; ++kt) {
        __syncthreads();
        // stage K (64x96) and V (96x64) tiles: 768 16B segs each, 3 per thread
#pragma unroll
        for (int it = 0; it < 3; ++it) {
            int idx = it * 256 + t;
            { int r = idx / 12, s8 = (idx % 12) * 8;
              *(uint4_a*)&lK[r * 104 + s8] = *(const uint4_a*)&Kb[(size_t)(kt * 64 + r) * HDIM + s8]; }
            { int r = idx >> 3, s8 = (idx & 7) * 8;
              *(uint4_a*)&lV[r * 72 + s8] = *(const uint4_a*)&Vb[(size_t)r * SEQ + kt * 64 + s8]; }
        }
        __syncthreads();

        // S = Qs*K^T : wave covers 32 q-rows (2 m-frags) x 64 keys
        fx4 accS[2][4] = {};
#pragma unroll
        for (int kd = 0; kd < 3; ++kd) {
#pragma unroll
            for (int j = 0; j < 4; ++j) {
                bf16x8 bk = *(const bf16x8_a*)&lK[(j * 16 + lx) * 104 + kd * 32 + quad * 8];
                accS[0][j] = __builtin_amdgcn_mfma_f32_16x16x32_bf16(aq[0][kd], bk, accS[0][j], 0, 0, 0);
                accS[1][j] = __builtin_amdgcn_mfma_f32_16x16x32_bf16(aq[1][kd], bk, accS[1][j], 0, 0, 0);
            }
        }

        // preload V fragments once (shared across both m half-passes)
        bf16x8 bv[2][6];
#pragma unroll
        for (int kk = 0; kk < 2; ++kk)
#pragma unroll
            for (int d = 0; d < 6; ++d)
                bv[kk][d] = *(const bf16x8_a*)&lV[(d * 16 + lx) * 72 + kk * 32 + quad * 8];

        // two half-passes over m-frags, reusing lP[wave]
#pragma unroll
        for (int i = 0; i < 2; ++i) {
#pragma unroll
            for (int r = 0; r < 4; ++r) {
#pragma unroll
                for (int j = 0; j < 4; ++j) {
                    float p = fexp2(accS[i][j][r]);   // 2^x, log2e folded into Q
                    lsum[i][r] += p;
                    lP[wave][(quad * 4 + r) * 72 + j * 16 + lx] = f2bf(p);
                }
            }
            asm volatile("s_waitcnt lgkmcnt(0)" ::: "memory");  // wave-private lP drained
#pragma unroll
            for (int kk = 0; kk < 2; ++kk) {
                bf16x8 ap = *(const bf16x8_a*)&lP[wave][lx * 72 + kk * 32 + quad * 8];
#pragma unroll
                for (int d = 0; d < 6; ++d)
                    accO[i][d] = __builtin_amdgcn_mfma_f32_16x16x32_bf16(ap, bv[kk][d], accO[i][d], 0, 0, 0);
            }
        }
    }

    // epilogue
#pragma unroll
    for (int i = 0; i < 2; ++i) {
#pragma unroll
        for (int r = 0; r < 4; ++r) {
            float s = lsum[i][r];
#pragma unroll
            for (int off = 1; off < 16; off <<= 1) s += __shfl_xor(s, off, 64);
            const float inv = 1.0f / s;
            const int nseq = qt * 128 + wave * 32 + i * 16 + quad * 4 + r;
            ushort_t* orow = O + ((size_t)(b * SEQ + nseq)) * EMB + h * HDIM;
#pragma unroll
            for (int d = 0; d < 6; ++d)
                orow[d * 16 + lx] = f2bf(accO[i][d][r] * inv);
        }
    }
}

// ---------------- projection: Ob bf16 [8192][768] @ Wt2^T + bias -> f32 out ----------------
__global__ __launch_bounds__(256, 2) void proj_gemm(
        const ushort_t* __restrict__ A, const ushort_t* __restrict__ Wt2,
        const void* __restrict__ bias, float* __restrict__ out,
        const int* __restrict__ flag)
{
    constexpr int KDIM = EMB;
    __shared__ __attribute__((aligned(16))) ushort_t lA[128 * 32];
    __shared__ __attribute__((aligned(16))) ushort_t lB[128 * 32];
    const int t = threadIdx.x;
    const int m0 = blockIdx.x * 128, n0 = blockIdx.y * 128;
    const bool isf = (*flag != 0);
    const int lane = t & 63, wave = t >> 6;
    const int wm = (wave & 1) * 64, wn = (wave >> 1) * 64;
    const int lx = lane & 15, quad = lane >> 4;

    fx4 acc[4][4] = {};

    for (int kt = 0; kt < KDIM / 32; ++kt) {
        const int k0 = kt * 32;
        __syncthreads();
#pragma unroll
        for (int it = 0; it < 2; ++it) {
            int idx = it * 256 + t;
            int r = idx >> 2, s8 = (idx & 3) * 8;
            load_lds16(&A  [(size_t)(m0 + r) * KDIM + k0 + s8], &lA[idx * 8]);
            load_lds16(&Wt2[(size_t)(n0 + r) * KDIM + k0 + s8], &lB[idx * 8]);
        }
        __syncthreads();

        bf16x8 af[4], bfr[4];
#pragma unroll
        for (int i = 0; i < 4; ++i)
            af[i] = *(const bf16x8_a*)&lA[(wm + i * 16 + lx) * 32 + quad * 8];
#pragma unroll
        for (int j = 0; j < 4; ++j)
            bfr[j] = *(const bf16x8_a*)&lB[(wn + j * 16 + lx) * 32 + quad * 8];
#pragma unroll
        for (int i = 0; i < 4; ++i)
#pragma unroll
            for (int j = 0; j < 4; ++j)
                acc[i][j] = __builtin_amdgcn_mfma_f32_16x16x32_bf16(af[i], bfr[j], acc[i][j], 0, 0, 0);
    }

#pragma unroll
    for (int j = 0; j < 4; ++j) {
        const int c = n0 + wn + j * 16 + lx;
        const float bv = isf ? ((const float*)bias)[c] : bf2f(((const ushort_t*)bias)[c]);
#pragma unroll
        for (int i = 0; i < 4; ++i) {
            const int mr = m0 + wm + i * 16 + quad * 4;
#pragma unroll
            for (int r = 0; r < 4; ++r)
                out[(size_t)(mr + r) * EMB + c] = acc[i][j][r] + bv;   // f32 store
        }
    }
}

// ---------------- launch ----------------
extern "C" void kernel_launch(void* const* d_in, const int* in_sizes, int n_in,
                              void* d_out, int out_size, void* d_ws, size_t ws_size,
                              hipStream_t stream) {
    const void* x     = d_in[0];
    const void* Wqkv  = d_in[1];
    const void* bqkv  = d_in[2];
    const void* Wproj = d_in[3];
    const void* bproj = d_in[4];
    float* out = (float*)d_out;     // output is float32

    char* ws = (char*)d_ws;
    int* flag = (int*)ws;
    size_t off = 1024;
    ushort_t* Ob  = (ushort_t*)(ws + off);  off += (size_t)MROWS * EMB * 2;   // 12.58 MB
    ushort_t* Xc  = (ushort_t*)(ws + off);  off += (size_t)MROWS * EMB * 2;   // 12.58 MB
    ushort_t* Wt1 = (ushort_t*)(ws + off);  off += (size_t)2304 * EMB * 2;    //  3.54 MB
    ushort_t* Wt2 = (ushort_t*)(ws + off);  off += (size_t)EMB * EMB * 2;     //  1.18 MB
    ushort_t* stage = (ushort_t*)(ws + off);
    const size_t SLOT_BYTES = (size_t)3 * SEQ * HDIM * 2;   // 1.18 MB per (b,h) unit
    size_t avail = ws_size > off ? ws_size - off : 0;
    int G = (int)(avail / SLOT_BYTES);
    if (G < 1) G = 1;
    if (G > 32) G = 32;

    detect_f32<<<1, 256, 0, stream>>>((const uint32_t*)x, flag);
    canon_x<<<dim3(MROWS * EMB / (256 * 8)), 256, 0, stream>>>(x, Xc, flag);
    transpose_conv<<<dim3(2304 / 64, EMB / 64), 256, 0, stream>>>(Wqkv, Wt1, EMB, 2304, flag,
                                                                 (G == 32) ? 1 : 0);
    transpose_conv<<<dim3(EMB / 64, EMB / 64), 256, 0, stream>>>(Wproj, Wt2, EMB, EMB, flag, 0);
    if (G == 32) {
        // permuted-weight QKV: uniform sections, coalesced epilogue
        qkv_mfma_perm<<<dim3(64, 24), 256, 0, stream>>>(Xc, Wt1, bqkv, stage, flag);
        attn_flash<<<dim3(SEQ / 128, 32), 256, 0, stream>>>(stage, Ob, 0);
    } else {
        for (int u0 = 0; u0 < 32; u0 += G) {
            const int gc = (32 - u0 < G) ? (32 - u0) : G;
            qkv_mfma<<<dim3(16, 3, gc), 256, 0, stream>>>(Xc, Wt1, bqkv, stage, u0, flag);
            attn_flash<<<dim3(SEQ / 128, gc), 256, 0, stream>>>(stage, Ob, u0);
        }
    }
    proj_gemm<<<dim3(MROWS / 128, EMB / 128), 256, 0, stream>>>(Ob, Wt2, bproj, out, flag);
}

// Round 8
// 239.597 us; speedup vs baseline: 1.0964x; 1.0383x over previous
//
#include <hip/hip_runtime.h>
#include <hip/hip_bf16.h>
#include <stdint.h>

#define EMB   768
#define HEADS 8
#define HDIM  96
#define SEQ   2048
#define BATCH 4
#define MROWS (BATCH*SEQ)     // 8192

typedef unsigned short ushort_t;
typedef __bf16 bf16x8 __attribute__((ext_vector_type(8)));
typedef float  fx4    __attribute__((ext_vector_type(4)));
typedef uint4  uint4_a  __attribute__((may_alias));
typedef uint2  uint2_a  __attribute__((may_alias));
typedef bf16x8 bf16x8_a __attribute__((may_alias));

__device__ __forceinline__ float bf2f(ushort_t u) {
    uint32_t v = ((uint32_t)u) << 16;
    return __builtin_bit_cast(float, v);
}
__device__ __forceinline__ ushort_t f2bf(float f) {
    uint32_t u = __builtin_bit_cast(uint32_t, f);
    u += 0x7fffu + ((u >> 16) & 1u);   // RNE
    return (ushort_t)(u >> 16);
}
// packed f32x2 -> bf16x2 (v_cvt_pk_bf16_f32); memcpy: __hip_bfloat162 not trivially copyable
__device__ __forceinline__ uint32_t pk2(float a, float b) {
    __hip_bfloat162 h = __float22bfloat162_rn(make_float2(a, b));
    uint32_t r;
    __builtin_memcpy(&r, &h, 4);
    return r;
}
// raw 2^x (input pre-scaled by log2e in the Q projection)
__device__ __forceinline__ float fexp2(float x) {
    float r;
    asm("v_exp_f32 %0, %1" : "=v"(r) : "v"(x));
    return r;
}
// async global->LDS, 16B/lane; LDS dest must be wave-uniform base + lane*16
__device__ __forceinline__ void load_lds16(const void* g, void* l) {
    __builtin_amdgcn_global_load_lds(
        (const __attribute__((address_space(1))) uint32_t*)g,
        (__attribute__((address_space(3))) uint32_t*)l, 16, 0, 0);
}

// flag=1 -> input words are f32; flag=0 -> packed bf16
__global__ __launch_bounds__(256) void detect_f32(const uint32_t* __restrict__ x,
                                                  int* __restrict__ flag) {
    __shared__ int cnt;
    if (threadIdx.x == 0) cnt = 0;
    __syncthreads();
    int local = 0;
    for (int i = threadIdx.x; i < 4096; i += 256) {
        uint32_t e = (x[i] >> 7) & 0xFFu;
        local += (e >= 64u && e <= 143u) ? 1 : 0;
    }
    atomicAdd(&cnt, local);
    __syncthreads();
    if (threadIdx.x == 0) *flag = (cnt < 3500) ? 1 : 0;
}

// ---------------- canonicalize x to bf16 (8 elems/thread) ----------------
__global__ __launch_bounds__(256) void canon_x(const void* __restrict__ src,
        ushort_t* __restrict__ dst, const int* __restrict__ flag) {
    const int i = (blockIdx.x * 256 + threadIdx.x) * 8;
    if (*flag) {
        const float* s = (const float*)src + i;
        float4 a = *(const float4*)s, b = *(const float4*)(s + 4);
        uint32_t tmp[4] = { pk2(a.x, a.y), pk2(a.z, a.w), pk2(b.x, b.y), pk2(b.z, b.w) };
        *(uint4_a*)&dst[i] = *(const uint4_a*)tmp;
    } else {
        *(uint4_a*)&dst[i] = *(const uint4_a*)((const ushort_t*)src + i);
    }
}

// ---------------- weight transpose (+f32->bf16): src[R][C] -> dst[C'][R] bf16 ---------
// permQKV=1: destination row for src column c is n = h*288 + s*96 + dd
// (h=c/288, dd=(c%288)/3, s=c%3) -- de-interleaves the fused qkv so the GEMM's
// N dimension becomes contiguous {Q|K|V} sections (kills the epilogue scatter).
__global__ __launch_bounds__(256) void transpose_conv(
        const void* __restrict__ vsrc, ushort_t* __restrict__ dst,
        int R, int C, const int* __restrict__ flag, int permQKV)
{
    __shared__ __attribute__((aligned(16))) ushort_t tile[64][72];
    const int c0 = blockIdx.x * 64, r0 = blockIdx.y * 64;
    const int t = threadIdx.x;
    const int isf32 = *flag;
#pragma unroll
    for (int i = 0; i < 2; ++i) {
        int idx = i * 256 + t;
        int r = idx >> 3, c8 = (idx & 7) * 8;
        if (isf32) {
            const float* s = (const float*)vsrc + (size_t)(r0 + r) * C + c0 + c8;
            float4 v0 = *(const float4*)s, v1 = *(const float4*)(s + 4);
            uint32_t tmp[4] = { pk2(v0.x, v0.y), pk2(v0.z, v0.w),
                                pk2(v1.x, v1.y), pk2(v1.z, v1.w) };
            *(uint4_a*)&tile[r][c8] = *(const uint4_a*)tmp;
        } else {
            const ushort_t* s = (const ushort_t*)vsrc + (size_t)(r0 + r) * C + c0 + c8;
            *(uint4_a*)&tile[r][c8] = *(const uint4_a*)s;
        }
    }
    __syncthreads();
#pragma unroll
    for (int i = 0; i < 2; ++i) {
        int idx = i * 256 + t;
        int r = idx >> 3, k8 = (idx & 7) * 8;
        ushort_t tmp[8];
#pragma unroll
        for (int j = 0; j < 8; ++j) tmp[j] = tile[k8 + j][r];
        int cdst = c0 + r;
        if (permQKV) {
            int h = cdst / 288, rem = cdst - h * 288;
            cdst = h * 288 + (rem % 3) * 96 + rem / 3;
        }
        *(uint4_a*)&dst[(size_t)cdst * R + r0 + k8] = *(const uint4_a*)tmp;
    }
}

// ---------------- QKV GEMM, permuted weights, section tiles, BK=64 ----------------
// grid (64, 24) = 1536 blocks; tile 128(M) x 96(N); BK=64 via DUAL 32-wide buffers
// (each keeps the proven [rows][32] layout/access pattern; barrier count halves:
// 12 K-steps x 24 MFMA vs 24 x 12 -- each __syncthreads costs a full vmcnt drain).
// Epilogue lT ALIASES the main-loop buffers (28 KB LDS total, barrier before reuse);
// coalesced 16B/lane stores (round-7: removed the 84MB-FETCH/94MB-WRITE scatter).
// Bijective XCD swizzle: 192 consecutive flat ids per XCD.
__global__ __launch_bounds__(256, 2) void qkv_mfma_perm(
        const ushort_t* __restrict__ Xc, const ushort_t* __restrict__ Wt1p,
        const void* __restrict__ bias,
        ushort_t* __restrict__ stage, const int* __restrict__ flag)
{
    __shared__ __attribute__((aligned(16))) ushort_t lsh[14336];  // 28 KB
    ushort_t* lA0 = lsh;            // [128][32]  8 KB
    ushort_t* lA1 = lsh + 4096;     // [128][32]  8 KB
    ushort_t* lB0 = lsh + 8192;     // [96][32]   6 KB
    ushort_t* lB1 = lsh + 11264;    // [96][32]   6 KB
    ushort_t* lT  = lsh;            // 13312 elems, epilogue repack (aliases)
    const int t = threadIdx.x;
    const int flat = blockIdx.y * 64 + blockIdx.x;     // [0,1536)
    const int nf = (flat & 7) * 192 + (flat >> 3);     // bijective XCD swizzle
    const int mt = nf & 63, sec = nf >> 6;             // m-tile, section h*3+s
    const int h = sec / 3, s = sec - h * 3;
    const int m0 = mt * 128;
    const bool isf = (*flag != 0);
    const int lane = t & 63, wave = t >> 6;
    const int lx = lane & 15, quad = lane >> 4;
    const int wm = (wave & 1) * 64, wn = (wave >> 1) * 48;
    const float qscale = 0.0520587734f;   // log2(e)/sqrt(768)

    fx4 acc[4][3] = {};

    for (int kt = 0; kt < EMB / 64; ++kt) {
        const int k0 = kt * 64;
        __syncthreads();
        // A tiles via DMA: 2 x 512 segs (128 rows x 4 each)
#pragma unroll
        for (int it = 0; it < 2; ++it) {
            int idx = it * 256 + t;
            int r = idx >> 2, k8 = (idx & 3) * 8;
            load_lds16(&Xc[(size_t)(m0 + r) * EMB + k0 + k8],      &lA0[idx * 8]);
            load_lds16(&Xc[(size_t)(m0 + r) * EMB + k0 + 32 + k8], &lA1[idx * 8]);
        }
        // B tiles via DMA: 2 x 384 segs (96 rows x 4 each), rows sec*96 + c
        {
            int c = t >> 2, s8 = (t & 3) * 8;
            load_lds16(&Wt1p[(size_t)(sec * 96 + c) * EMB + k0 + s8],      &lB0[t * 8]);
            load_lds16(&Wt1p[(size_t)(sec * 96 + c) * EMB + k0 + 32 + s8], &lB1[t * 8]);
            if (t < 128) {
                int idx = 256 + t;
                int c2 = idx >> 2, s82 = (idx & 3) * 8;
                load_lds16(&Wt1p[(size_t)(sec * 96 + c2) * EMB + k0 + s82],      &lB0[idx * 8]);
                load_lds16(&Wt1p[(size_t)(sec * 96 + c2) * EMB + k0 + 32 + s82], &lB1[idx * 8]);
            }
        }
        __syncthreads();

        // two BK=32 sub-steps from the dual buffers: 24 MFMA per barrier pair
#pragma unroll
        for (int sub = 0; sub < 2; ++sub) {
            const ushort_t* A = sub ? lA1 : lA0;
            const ushort_t* B = sub ? lB1 : lB0;
            bf16x8 af[4], bfr[3];
#pragma unroll
            for (int i = 0; i < 4; ++i)
                af[i] = *(const bf16x8_a*)&A[(wm + i * 16 + lx) * 32 + quad * 8];
#pragma unroll
            for (int j = 0; j < 3; ++j)
                bfr[j] = *(const bf16x8_a*)&B[(wn + j * 16 + lx) * 32 + quad * 8];
#pragma unroll
            for (int i = 0; i < 4; ++i)
#pragma unroll
                for (int j = 0; j < 3; ++j)
                    acc[i][j] = __builtin_amdgcn_mfma_f32_16x16x32_bf16(af[i], bfr[j], acc[i][j], 0, 0, 0);
        }
    }

    __syncthreads();   // all waves done reading lA/lB before lT (aliased) is written

    // ---- coalesced epilogue via LDS repack ----
    // C/D frag: col dd = wn + j*16 + lx, row = wm + i*16 + quad*4 + r.
    const int b8 = (m0 >> 11) * 8, mrow = m0 & 2047;   // 128-row tiles never straddle a batch
    ushort_t* base = stage + (size_t)(b8 + h) * (3 * SEQ * HDIM);
    if (s < 2) {
        // Q/K: lT row-major [128][104 pad], then 16B stores of [nseq][96] rows
        ushort_t* dstQK = base + (size_t)s * SEQ * HDIM;
        const float sc = (s == 0) ? qscale : 1.0f;
#pragma unroll
        for (int j = 0; j < 3; ++j) {
            const int dd = wn + j * 16 + lx;
            const int c = h * 288 + dd * 3 + s;        // original column for bias
            const float bv = isf ? ((const float*)bias)[c]
                                 : bf2f(((const ushort_t*)bias)[c]);
#pragma unroll
            for (int i = 0; i < 4; ++i)
#pragma unroll
                for (int r = 0; r < 4; ++r)
                    lT[(wm + i * 16 + quad * 4 + r) * 104 + dd] = f2bf((acc[i][j][r] + bv) * sc);
        }
        __syncthreads();
#pragma unroll
        for (int it = 0; it < 6; ++it) {
            int idx = it * 256 + t;                    // 1536 segs = 128 rows x 12
            int r = idx / 12, s8 = (idx % 12) * 8;
            *(uint4_a*)&dstQK[(size_t)(mrow + r) * HDIM + s8] = *(const uint4_a*)&lT[r * 104 + s8];
        }
    } else {
        // V: lT transposed [96][136 pad], then 16B stores of [dd][2048] chunks
        ushort_t* Vg = base + 2 * SEQ * HDIM;
#pragma unroll
        for (int j = 0; j < 3; ++j) {
            const int dd = wn + j * 16 + lx;
            const int c = h * 288 + dd * 3 + 2;
            const float bv = isf ? ((const float*)bias)[c]
                                 : bf2f(((const ushort_t*)bias)[c]);
#pragma unroll
            for (int i = 0; i < 4; ++i)
#pragma unroll
                for (int r = 0; r < 4; ++r)
                    lT[dd * 136 + wm + i * 16 + quad * 4 + r] = f2bf(acc[i][j][r] + bv);
        }
        __syncthreads();
#pragma unroll
        for (int it = 0; it < 6; ++it) {
            int idx = it * 256 + t;                    // 1536 segs = 96 rows x 16
            int dd = idx >> 4, s8 = (idx & 15) * 8;
            *(uint4_a*)&Vg[(size_t)dd * SEQ + mrow + s8] = *(const uint4_a*)&lT[dd * 136 + s8];
        }
    }
}

// ---------------- per-head QKV GEMM (fallback when G < 32; unpermuted Wt1) --------
__global__ __launch_bounds__(256, 2) void qkv_mfma(
        const ushort_t* __restrict__ Xc, const ushort_t* __restrict__ Wt1,
        const void* __restrict__ bias,
        ushort_t* __restrict__ stage, int u0, const int* __restrict__ flag)
{
    __shared__ __attribute__((aligned(16))) ushort_t lA[128 * 32];
    __shared__ __attribute__((aligned(16))) ushort_t lB[96 * 32];
    const int g = blockIdx.z, u = u0 + g;
    const int b = u >> 3, h = u & 7;
    const int m0 = blockIdx.x * 128;
    const int n0 = blockIdx.y * 96;
    const bool isf = (*flag != 0);
    const int t = threadIdx.x, lane = t & 63, wave = t >> 6;
    const int lx = lane & 15, quad = lane >> 4;
    const int wm = (wave & 1) * 64, wn = (wave >> 1) * 48;
    const int hb = h * 288;
    const size_t xrow0 = (size_t)(b * SEQ + m0) * EMB;
    const float qscale = 0.0520587734f;   // log2(e)/sqrt(768)

    ushort_t* Qg = stage + (size_t)g * (3 * SEQ * HDIM);
    ushort_t* Kg = Qg + SEQ * HDIM;
    ushort_t* Vg = Qg + 2 * SEQ * HDIM;

    fx4 acc[4][3] = {};

    for (int kt = 0; kt < EMB / 32; ++kt) {
        const int k0 = kt * 32;
        __syncthreads();
#pragma unroll
        for (int it = 0; it < 2; ++it) {
            int idx = it * 256 + t;
            int r = idx >> 2, k8 = (idx & 3) * 8;
            load_lds16(&Xc[xrow0 + (size_t)r * EMB + k0 + k8], &lA[idx * 8]);
        }
        {
            int c = t >> 2, s8 = (t & 3) * 8;
            load_lds16(&Wt1[(size_t)(hb + n0 + c) * EMB + k0 + s8], &lB[t * 8]);
            if (t < 128) {
                int idx = 256 + t;
                int c2 = idx >> 2, s82 = (idx & 3) * 8;
                load_lds16(&Wt1[(size_t)(hb + n0 + c2) * EMB + k0 + s82], &lB[idx * 8]);
            }
        }
        __syncthreads();

        bf16x8 af[4], bfr[3];
#pragma unroll
        for (int i = 0; i < 4; ++i)
            af[i] = *(const bf16x8_a*)&lA[(wm + i * 16 + lx) * 32 + quad * 8];
#pragma unroll
        for (int j = 0; j < 3; ++j)
            bfr[j] = *(const bf16x8_a*)&lB[(wn + j * 16 + lx) * 32 + quad * 8];
#pragma unroll
        for (int i = 0; i < 4; ++i)
#pragma unroll
            for (int j = 0; j < 3; ++j)
                acc[i][j] = __builtin_amdgcn_mfma_f32_16x16x32_bf16(af[i], bfr[j], acc[i][j], 0, 0, 0);
    }

#pragma unroll
    for (int j = 0; j < 3; ++j) {
        const int cl = n0 + wn + j * 16 + lx;
        const int dd = cl / 3, s = cl - dd * 3;
        const float bv = isf ? ((const float*)bias)[hb + cl]
                             : bf2f(((const ushort_t*)bias)[hb + cl]);
#pragma unroll
        for (int i = 0; i < 4; ++i) {
            const int ml = m0 + wm + i * 16 + quad * 4;
#pragma unroll
            for (int r = 0; r < 4; ++r) {
                const int nseq = ml + r;
                const float v = acc[i][j][r] + bv;
                if (s == 0)      Qg[(size_t)nseq * HDIM + dd] = f2bf(v * qscale);
                else if (s == 1) Kg[(size_t)nseq * HDIM + dd] = f2bf(v);
                else             Vg[(size_t)dd * SEQ + nseq] = f2bf(v);
            }
        }
    }
}

// ---------------- flash attention v2: 128 q-rows/block, 32 q-rows/wave ----------------
// grid (SEQ/128=16, gc). Proven 2-barrier staging structure (round-3, 84.4us):
//  * Q held in registers (loaded once from global)
//  * XCD swizzle (FETCH_SIZE -79%, K/V L2-resident)
//  * softmax via raw v_exp_f32 (log2e folded into Q scale upstream)
// LDS 35.5 KB; occupancy VGPR-capped at 2 blocks/CU.  [UNCHANGED - control]
__global__ __launch_bounds__(256, 2) void attn_flash(
        const ushort_t* __restrict__ stage, ushort_t* __restrict__ O, int u0)
{
    __shared__ __attribute__((aligned(16))) ushort_t lK[64 * 104];   // 13.0 KB
    __shared__ __attribute__((aligned(16))) ushort_t lV[96 * 72];    // 13.5 KB
    __shared__ __attribute__((aligned(16))) ushort_t lP[4][16 * 72]; //  9.0 KB wave-private
    const int t = threadIdx.x, lane = t & 63, wave = t >> 6;
    const int lx = lane & 15, quad = lane >> 4;
    int qt = blockIdx.x, g = blockIdx.y;
    if (gridDim.y == 32) {
        // XCD-aware swizzle (bijective on the 16x32 grid): each XCD owns 4
        // consecutive (b,h) units -> all 16 q-blocks of a unit share one L2.
        int L = blockIdx.y * 16 + blockIdx.x;
        int xcd = L & 7, i = L >> 3;
        g = xcd * 4 + (i >> 4);
        qt = i & 15;
    }
    const int u = u0 + g;
    const int b = u >> 3, h = u & 7;
    const ushort_t* Qb = stage + (size_t)g * (3 * SEQ * HDIM);
    const ushort_t* Kb = Qb + SEQ * HDIM;
    const ushort_t* Vb = Qb + 2 * SEQ * HDIM;

    // ---- Q fragments in registers, loaded once from global ----
    bf16x8 aq[2][3];
#pragma unroll
    for (int i = 0; i < 2; ++i)
#pragma unroll
        for (int kd = 0; kd < 3; ++kd)
            aq[i][kd] = *(const bf16x8_a*)
                &Qb[(size_t)(qt * 128 + wave * 32 + i * 16 + lx) * HDIM + kd * 32 + quad * 8];

    fx4 accO[2][6] = {};
    float lsum[2][4] = {};

    for (int kt = 0; kt < SEQ / 64; ++kt) {
        __syncthreads();
        // stage K (64x96) and V (96x64) tiles: 768 16B segs each, 3 per thread
#pragma unroll
        for (int it = 0; it < 3; ++it) {
            int idx = it * 256 + t;
            { int r = idx / 12, s8 = (idx % 12) * 8;
              *(uint4_a*)&lK[r * 104 + s8] = *(const uint4_a*)&Kb[(size_t)(kt * 64 + r) * HDIM + s8]; }
            { int r = idx >> 3, s8 = (idx & 7) * 8;
              *(uint4_a*)&lV[r * 72 + s8] = *(const uint4_a*)&Vb[(size_t)r * SEQ + kt * 64 + s8]; }
        }
        __syncthreads();

        // S = Qs*K^T : wave covers 32 q-rows (2 m-frags) x 64 keys
        fx4 accS[2][4] = {};
#pragma unroll
        for (int kd = 0; kd < 3; ++kd) {
#pragma unroll
            for (int j = 0; j < 4; ++j) {
                bf16x8 bk = *(const bf16x8_a*)&lK[(j * 16 + lx) * 104 + kd * 32 + quad * 8];
                accS[0][j] = __builtin_amdgcn_mfma_f32_16x16x32_bf16(aq[0][kd], bk, accS[0][j], 0, 0, 0);
                accS[1][j] = __builtin_amdgcn_mfma_f32_16x16x32_bf16(aq[1][kd], bk, accS[1][j], 0, 0, 0);
            }
        }

        // preload V fragments once (shared across both m half-passes)
        bf16x8 bv[2][6];
#pragma unroll
        for (int kk = 0; kk < 2; ++kk)
#pragma unroll
            for (int d = 0; d < 6; ++d)
                bv[kk][d] = *(const bf16x8_a*)&lV[(d * 16 + lx) * 72 + kk * 32 + quad * 8];

        // two half-passes over m-frags, reusing lP[wave]
#pragma unroll
        for (int i = 0; i < 2; ++i) {
#pragma unroll
            for (int r = 0; r < 4; ++r) {
#pragma unroll
                for (int j = 0; j < 4; ++j) {
                    float p = fexp2(accS[i][j][r]);   // 2^x, log2e folded into Q
                    lsum[i][r] += p;
                    lP[wave][(quad * 4 + r) * 72 + j * 16 + lx] = f2bf(p);
                }
            }
            asm volatile("s_waitcnt lgkmcnt(0)" ::: "memory");  // wave-private lP drained
#pragma unroll
            for (int kk = 0; kk < 2; ++kk) {
                bf16x8 ap = *(const bf16x8_a*)&lP[wave][lx * 72 + kk * 32 + quad * 8];
#pragma unroll
                for (int d = 0; d < 6; ++d)
                    accO[i][d] = __builtin_amdgcn_mfma_f32_16x16x32_bf16(ap, bv[kk][d], accO[i][d], 0, 0, 0);
            }
        }
    }

    // epilogue
#pragma unroll
    for (int i = 0; i < 2; ++i) {
#pragma unroll
        for (int r = 0; r < 4; ++r) {
            float s = lsum[i][r];
#pragma unroll
            for (int off = 1; off < 16; off <<= 1) s += __shfl_xor(s, off, 64);
            const float inv = 1.0f / s;
            const int nseq = qt * 128 + wave * 32 + i * 16 + quad * 4 + r;
            ushort_t* orow = O + ((size_t)(b * SEQ + nseq)) * EMB + h * HDIM;
#pragma unroll
            for (int d = 0; d < 6; ++d)
                orow[d * 16 + lx] = f2bf(accO[i][d][r] * inv);
        }
    }
}

// ---------------- projection: Ob bf16 [8192][768] @ Wt2^T + bias -> f32 out --------
// BK=64 via dual 32-wide buffers (32 MFMA per barrier pair, 12 K-steps) +
// bijective XCD swizzle (384 = 8 x 48).
__global__ __launch_bounds__(256, 2) void proj_gemm(
        const ushort_t* __restrict__ A, const ushort_t* __restrict__ Wt2,
        const void* __restrict__ bias, float* __restrict__ out,
        const int* __restrict__ flag)
{
    constexpr int KDIM = EMB;
    __shared__ __attribute__((aligned(16))) ushort_t lsh[16384];  // 32 KB
    ushort_t* lA0 = lsh;            // [128][32]
    ushort_t* lA1 = lsh + 4096;
    ushort_t* lB0 = lsh + 8192;
    ushort_t* lB1 = lsh + 12288;
    const int t = threadIdx.x;
    const int flat = blockIdx.y * 64 + blockIdx.x;    // grid (64,6) -> [0,384)
    const int nf = (flat & 7) * 48 + (flat >> 3);     // bijective XCD swizzle
    const int m0 = (nf % 64) * 128, n0 = (nf / 64) * 128;
    const bool isf = (*flag != 0);
    const int lane = t & 63, wave = t >> 6;
    const int wm = (wave & 1) * 64, wn = (wave >> 1) * 64;
    const int lx = lane & 15, quad = lane >> 4;

    fx4 acc[4][4] = {};

    for (int kt = 0; kt < KDIM / 64; ++kt) {
        const int k0 = kt * 64;
        __syncthreads();
#pragma unroll
        for (int it = 0; it < 2; ++it) {
            int idx = it * 256 + t;
            int r = idx >> 2, s8 = (idx & 3) * 8;
            load_lds16(&A  [(size_t)(m0 + r) * KDIM + k0 + s8],      &lA0[idx * 8]);
            load_lds16(&A  [(size_t)(m0 + r) * KDIM + k0 + 32 + s8], &lA1[idx * 8]);
            load_lds16(&Wt2[(size_t)(n0 + r) * KDIM + k0 + s8],      &lB0[idx * 8]);
            load_lds16(&Wt2[(size_t)(n0 + r) * KDIM + k0 + 32 + s8], &lB1[idx * 8]);
        }
        __syncthreads();

#pragma unroll
        for (int sub = 0; sub < 2; ++sub) {
            const ushort_t* Abuf = sub ? lA1 : lA0;
            const ushort_t* Bbuf = sub ? lB1 : lB0;
            bf16x8 af[4], bfr[4];
#pragma unroll
            for (int i = 0; i < 4; ++i)
                af[i] = *(const bf16x8_a*)&Abuf[(wm + i * 16 + lx) * 32 + quad * 8];
#pragma unroll
            for (int j = 0; j < 4; ++j)
                bfr[j] = *(const bf16x8_a*)&Bbuf[(wn + j * 16 + lx) * 32 + quad * 8];
#pragma unroll
            for (int i = 0; i < 4; ++i)
#pragma unroll
                for (int j = 0; j < 4; ++j)
                    acc[i][j] = __builtin_amdgcn_mfma_f32_16x16x32_bf16(af[i], bfr[j], acc[i][j], 0, 0, 0);
        }
    }

#pragma unroll
    for (int j = 0; j < 4; ++j) {
        const int c = n0 + wn + j * 16 + lx;
        const float bv = isf ? ((const float*)bias)[c] : bf2f(((const ushort_t*)bias)[c]);
#pragma unroll
        for (int i = 0; i < 4; ++i) {
            const int mr = m0 + wm + i * 16 + quad * 4;
#pragma unroll
            for (int r = 0; r < 4; ++r)
                out[(size_t)(mr + r) * EMB + c] = acc[i][j][r] + bv;   // f32 store
        }
    }
}

// ---------------- launch ----------------
extern "C" void kernel_launch(void* const* d_in, const int* in_sizes, int n_in,
                              void* d_out, int out_size, void* d_ws, size_t ws_size,
                              hipStream_t stream) {
    const void* x     = d_in[0];
    const void* Wqkv  = d_in[1];
    const void* bqkv  = d_in[2];
    const void* Wproj = d_in[3];
    const void* bproj = d_in[4];
    float* out = (float*)d_out;     // output is float32

    char* ws = (char*)d_ws;
    int* flag = (int*)ws;
    size_t off = 1024;
    ushort_t* Ob  = (ushort_t*)(ws + off);  off += (size_t)MROWS * EMB * 2;   // 12.58 MB
    ushort_t* Xc  = (ushort_t*)(ws + off);  off += (size_t)MROWS * EMB * 2;   // 12.58 MB
    ushort_t* Wt1 = (ushort_t*)(ws + off);  off += (size_t)2304 * EMB * 2;    //  3.54 MB
    ushort_t* Wt2 = (ushort_t*)(ws + off);  off += (size_t)EMB * EMB * 2;     //  1.18 MB
    ushort_t* stage = (ushort_t*)(ws + off);
    const size_t SLOT_BYTES = (size_t)3 * SEQ * HDIM * 2;   // 1.18 MB per (b,h) unit
    size_t avail = ws_size > off ? ws_size - off : 0;
    int G = (int)(avail / SLOT_BYTES);
    if (G < 1) G = 1;
    if (G > 32) G = 32;

    detect_f32<<<1, 256, 0, stream>>>((const uint32_t*)x, flag);
    canon_x<<<dim3(MROWS * EMB / (256 * 8)), 256, 0, stream>>>(x, Xc, flag);
    transpose_conv<<<dim3(2304 / 64, EMB / 64), 256, 0, stream>>>(Wqkv, Wt1, EMB, 2304, flag,
                                                                 (G == 32) ? 1 : 0);
    transpose_conv<<<dim3(EMB / 64, EMB / 64), 256, 0, stream>>>(Wproj, Wt2, EMB, EMB, flag, 0);
    if (G == 32) {
        // permuted-weight QKV: uniform sections, coalesced epilogue
        qkv_mfma_perm<<<dim3(64, 24), 256, 0, stream>>>(Xc, Wt1, bqkv, stage, flag);
        attn_flash<<<dim3(SEQ / 128, 32), 256, 0, stream>>>(stage, Ob, 0);
    } else {
        for (int u0 = 0; u0 < 32; u0 += G) {
            const int gc = (32 - u0 < G) ? (32 - u0) : G;
            qkv_mfma<<<dim3(16, 3, gc), 256, 0, stream>>>(Xc, Wt1, bqkv, stage, u0, flag);
            attn_flash<<<dim3(SEQ / 128, gc), 256, 0, stream>>>(stage, Ob, u0);
        }
    }
    proj_gemm<<<dim3(MROWS / 128, EMB / 128), 256, 0, stream>>>(Ob, Wt2, bproj, out, flag);
}